// Round 2
// baseline (9337.769 us; speedup 1.0000x reference)
//
#include <hip/hip_runtime.h>
#include <math.h>

// Problem dims
#define BQ 8
#define SQ 512
#define HID 768
#define NH 12
#define DH 64
#define INTER 3072
#define NL 4
#define M_TOK (BQ*SQ)   // 4096 tokens

// ---------------------------------------------------------------------------
// prep: maskf[t] = mask, h = hidden * mask
// ---------------------------------------------------------------------------
__global__ __launch_bounds__(256) void prep_kernel(
    const float* __restrict__ hidden, const float* __restrict__ amask,
    float* __restrict__ maskf, float* __restrict__ h)
{
  int i = blockIdx.x * 256 + threadIdx.x;
  if (i < M_TOK * HID) {
    float m = amask[i / HID];
    h[i] = hidden[i] * m;
    if (i < M_TOK) maskf[i] = amask[i];
  }
}

// ---------------------------------------------------------------------------
// KERPLE bias table: kb[h][d] = d==0 ? 0 : -c1*log1p(c2 * d^c3)
// ---------------------------------------------------------------------------
__global__ void kerple_kernel(const float* __restrict__ r1,
                              const float* __restrict__ r2,
                              const float* __restrict__ r3,
                              float* __restrict__ kbt)
{
  int hh = blockIdx.x;       // head
  int d  = threadIdx.x;      // |i-j| in [0,512)
  float c1 = fmaxf(r1[hh], 1e-7f);
  float c2 = fmaxf(r2[hh], 1e-7f);
  float c3 = fmaxf(r3[hh], 1e-7f);
  float v = 0.0f;
  if (d > 0) v = -c1 * log1pf(c2 * powf((float)d, c3));
  kbt[hh * SQ + d] = v;
}

// ---------------------------------------------------------------------------
// C[M,N] = A[M,K] @ W[N,K]^T + bias(N), optional per-row scale (mask).
// 64x64 tile, BK=16, 256 threads, 4x4 per thread, fp32.
// ---------------------------------------------------------------------------
__global__ __launch_bounds__(256) void gemm_bias(
    const float* __restrict__ A, const float* __restrict__ W,
    const float* __restrict__ bias, const float* __restrict__ rowscale,
    float* __restrict__ C, int N, int K)
{
  __shared__ float As[16][65];
  __shared__ float Ws[16][65];
  int tid = threadIdx.x;
  int bn = blockIdx.x, bm = blockIdx.y;
  int tx = tid & 15, ty = tid >> 4;
  const float* Ab = A + (size_t)bm * 64 * K;
  const float* Wb = W + (size_t)bn * 64 * K;
  int ai = tid >> 2, ak = (tid & 3) * 4;   // 256 threads stage 64x16

  float acc[4][4] = {};
  for (int k0 = 0; k0 < K; k0 += 16) {
    float4 av = *reinterpret_cast<const float4*>(Ab + (size_t)ai * K + k0 + ak);
    As[ak+0][ai] = av.x; As[ak+1][ai] = av.y; As[ak+2][ai] = av.z; As[ak+3][ai] = av.w;
    float4 wv = *reinterpret_cast<const float4*>(Wb + (size_t)ai * K + k0 + ak);
    Ws[ak+0][ai] = wv.x; Ws[ak+1][ai] = wv.y; Ws[ak+2][ai] = wv.z; Ws[ak+3][ai] = wv.w;
    __syncthreads();
#pragma unroll
    for (int kk = 0; kk < 16; ++kk) {
      float a[4], w[4];
#pragma unroll
      for (int i = 0; i < 4; ++i) a[i] = As[kk][ty*4 + i];
#pragma unroll
      for (int j = 0; j < 4; ++j) w[j] = Ws[kk][tx*4 + j];
#pragma unroll
      for (int i = 0; i < 4; ++i)
#pragma unroll
        for (int j = 0; j < 4; ++j) acc[i][j] += a[i] * w[j];
    }
    __syncthreads();
  }
#pragma unroll
  for (int i = 0; i < 4; ++i) {
    int m = bm*64 + ty*4 + i;
    float rm = rowscale ? rowscale[m] : 1.0f;
#pragma unroll
    for (int j = 0; j < 4; ++j) {
      int n = bn*64 + tx*4 + j;
      float v = acc[i][j] + (bias ? bias[n] : 0.0f);
      C[(size_t)m * N + n] = v * rm;
    }
  }
}

// ---------------------------------------------------------------------------
// Fused GeGLU GEMM: X[m,n] = gelu_exact(A@Wa^T) * (A@Wb^T), n in [0,INTER)
// ---------------------------------------------------------------------------
__global__ __launch_bounds__(256) void gemm_glu(
    const float* __restrict__ A, const float* __restrict__ Wa,
    const float* __restrict__ Wb, float* __restrict__ X, int K)
{
  __shared__ float As [16][65];
  __shared__ float Wsa[16][65];
  __shared__ float Wsb[16][65];
  int tid = threadIdx.x;
  int bn = blockIdx.x, bm = blockIdx.y;
  int tx = tid & 15, ty = tid >> 4;
  const float* Ab  = A  + (size_t)bm * 64 * K;
  const float* Wab = Wa + (size_t)bn * 64 * K;
  const float* Wbb = Wb + (size_t)bn * 64 * K;
  int ai = tid >> 2, ak = (tid & 3) * 4;

  float acca[4][4] = {};
  float accb[4][4] = {};
  for (int k0 = 0; k0 < K; k0 += 16) {
    float4 av = *reinterpret_cast<const float4*>(Ab + (size_t)ai * K + k0 + ak);
    As[ak+0][ai] = av.x; As[ak+1][ai] = av.y; As[ak+2][ai] = av.z; As[ak+3][ai] = av.w;
    float4 wv = *reinterpret_cast<const float4*>(Wab + (size_t)ai * K + k0 + ak);
    Wsa[ak+0][ai] = wv.x; Wsa[ak+1][ai] = wv.y; Wsa[ak+2][ai] = wv.z; Wsa[ak+3][ai] = wv.w;
    float4 uv = *reinterpret_cast<const float4*>(Wbb + (size_t)ai * K + k0 + ak);
    Wsb[ak+0][ai] = uv.x; Wsb[ak+1][ai] = uv.y; Wsb[ak+2][ai] = uv.z; Wsb[ak+3][ai] = uv.w;
    __syncthreads();
#pragma unroll
    for (int kk = 0; kk < 16; ++kk) {
      float a[4], wa[4], wb[4];
#pragma unroll
      for (int i = 0; i < 4; ++i) a[i] = As[kk][ty*4 + i];
#pragma unroll
      for (int j = 0; j < 4; ++j) { wa[j] = Wsa[kk][tx*4 + j]; wb[j] = Wsb[kk][tx*4 + j]; }
#pragma unroll
      for (int i = 0; i < 4; ++i)
#pragma unroll
        for (int j = 0; j < 4; ++j) {
          acca[i][j] += a[i] * wa[j];
          accb[i][j] += a[i] * wb[j];
        }
    }
    __syncthreads();
  }
#pragma unroll
  for (int i = 0; i < 4; ++i) {
    int m = bm*64 + ty*4 + i;
#pragma unroll
    for (int j = 0; j < 4; ++j) {
      int n = bn*64 + tx*4 + j;
      float va = acca[i][j], vb = accb[i][j];
      float ge = 0.5f * va * (1.0f + erff(va * 0.70710678118654752440f));
      X[(size_t)m * INTER + n] = ge * vb;
    }
  }
}

// ---------------------------------------------------------------------------
// Attention: one block per (b, head, q-row). 512 threads.
// ---------------------------------------------------------------------------
__global__ __launch_bounds__(512) void attn_kernel(
    const float* __restrict__ qkv, const float* __restrict__ kbt,
    const float* __restrict__ maskf, float* __restrict__ attnb)
{
  __shared__ float qs[DH];
  __shared__ float probs[SQ];
  __shared__ float red[SQ];
  __shared__ float part[8][DH];
  int bid = blockIdx.x;
  int q  = bid & (SQ - 1);
  int t_ = bid >> 9;          // 0..95
  int hh = t_ % NH;
  int b  = t_ / NH;
  int tid = threadIdx.x;

  const float* qrow = qkv + ((size_t)(b*SQ + q)) * (3*HID) + hh*DH;  // Q
  if (tid < DH) qs[tid] = qrow[tid];
  __syncthreads();

  int j = tid;
  const float* Kr = qkv + ((size_t)(b*SQ + j)) * (3*HID) + HID + hh*DH; // K
  float dot = 0.0f;
#pragma unroll
  for (int d = 0; d < DH; ++d) dot += qs[d] * Kr[d];
  float s = dot * 0.125f
          + (1.0f - maskf[b*SQ + j]) * (-10000.0f)
          + kbt[hh*SQ + abs(q - j)];

  red[tid] = s; __syncthreads();
  for (int off = 256; off > 0; off >>= 1) {
    if (tid < off) red[tid] = fmaxf(red[tid], red[tid + off]);
    __syncthreads();
  }
  float mx = red[0]; __syncthreads();
  float p = expf(s - mx);
  red[tid] = p; __syncthreads();
  for (int off = 256; off > 0; off >>= 1) {
    if (tid < off) red[tid] += red[tid + off];
    __syncthreads();
  }
  float inv = 1.0f / red[0];
  probs[tid] = p * inv;
  __syncthreads();

  int d = tid & (DH - 1), c = tid >> 6;   // 8 chunks of 64 keys
  const float* Vb = qkv + ((size_t)(b*SQ + c*64)) * (3*HID) + 2*HID + hh*DH + d; // V
  float acc = 0.0f;
#pragma unroll 8
  for (int jj = 0; jj < 64; ++jj) acc += probs[c*64 + jj] * Vb[(size_t)jj * (3*HID)];
  part[c][d] = acc; __syncthreads();
  if (tid < DH) {
    float r = 0.0f;
#pragma unroll
    for (int cc = 0; cc < 8; ++cc) r += part[cc][tid];
    attnb[((size_t)(b*SQ + q)) * HID + hh*DH + tid] = r;
  }
}

// ---------------------------------------------------------------------------
// Residual + LayerNorm + mask: out = (LN(t + res)*g + b) * mask[row]
// ---------------------------------------------------------------------------
__global__ __launch_bounds__(256) void ln_res_kernel(
    const float* __restrict__ t, const float* __restrict__ res,
    const float* __restrict__ g, const float* __restrict__ bb,
    const float* __restrict__ maskf, float* __restrict__ out)
{
  __shared__ float red[256];
  int row = blockIdx.x, tid = threadIdx.x;
  const float* tp = t   + (size_t)row * HID;
  const float* rp = res + (size_t)row * HID;
  float y0 = tp[tid      ] + rp[tid      ];
  float y1 = tp[tid + 256] + rp[tid + 256];
  float y2 = tp[tid + 512] + rp[tid + 512];

  red[tid] = y0 + y1 + y2; __syncthreads();
  for (int off = 128; off > 0; off >>= 1) {
    if (tid < off) red[tid] += red[tid + off];
    __syncthreads();
  }
  float mu = red[0] * (1.0f / 768.0f); __syncthreads();
  float d0 = y0 - mu, d1 = y1 - mu, d2 = y2 - mu;
  red[tid] = d0*d0 + d1*d1 + d2*d2; __syncthreads();
  for (int off = 128; off > 0; off >>= 1) {
    if (tid < off) red[tid] += red[tid + off];
    __syncthreads();
  }
  float rstd = rsqrtf(red[0] * (1.0f / 768.0f) + 1e-12f);
  float mk = maskf[row];
  out[(size_t)row*HID + tid      ] = (d0*rstd*g[tid      ] + bb[tid      ]) * mk;
  out[(size_t)row*HID + tid + 256] = (d1*rstd*g[tid + 256] + bb[tid + 256]) * mk;
  out[(size_t)row*HID + tid + 512] = (d2*rstd*g[tid + 512] + bb[tid + 512]) * mk;
}

// ---------------------------------------------------------------------------
__global__ __launch_bounds__(256) void copy_out_kernel(
    const float* __restrict__ h, float* __restrict__ out)
{
  int i = blockIdx.x * 256 + threadIdx.x;
  if (i < M_TOK * HID) out[i] = h[i];
}

// ---------------------------------------------------------------------------
extern "C" void kernel_launch(void* const* d_in, const int* in_sizes, int n_in,
                              void* d_out, int out_size, void* d_ws, size_t ws_size,
                              hipStream_t stream) {
  const float* hidden     = (const float*)d_in[0];
  const float* amask      = (const float*)d_in[1];
  const float* Wqkv_w     = (const float*)d_in[2];
  const float* Wqkv_b     = (const float*)d_in[3];
  const float* attn_out_w = (const float*)d_in[4];
  const float* attn_out_b = (const float*)d_in[5];
  const float* ln1_g      = (const float*)d_in[6];
  const float* ln1_b      = (const float*)d_in[7];
  const float* glu_w      = (const float*)d_in[8];
  const float* wo_w       = (const float*)d_in[9];
  const float* wo_b       = (const float*)d_in[10];
  const float* ln2_g      = (const float*)d_in[11];
  const float* ln2_b      = (const float*)d_in[12];
  const float* r1         = (const float*)d_in[13];
  const float* r2         = (const float*)d_in[14];
  const float* r3         = (const float*)d_in[15];

  // fp32 workspace layout (floats)
  float* ws    = (float*)d_ws;
  float* maskf = ws;                         // 4096
  float* h     = maskf + 4096;               // 4096*768
  float* qkvb  = h     + (size_t)M_TOK*HID;  // 4096*2304
  float* attnb = qkvb  + (size_t)M_TOK*3*HID;// 4096*768
  float* ao    = attnb + (size_t)M_TOK*HID;  // 4096*768
  float* tbuf  = ao    + (size_t)M_TOK*HID;  // 4096*768
  float* xbuf  = tbuf  + (size_t)M_TOK*HID;  // 4096*3072
  float* kbt   = xbuf  + (size_t)M_TOK*INTER;// 12*512

  prep_kernel<<<(M_TOK*HID + 255)/256, 256, 0, stream>>>(hidden, amask, maskf, h);

  for (int l = 0; l < NL; ++l) {
    kerple_kernel<<<NH, SQ, 0, stream>>>(r1 + l*NH, r2 + l*NH, r3 + l*NH, kbt);

    // QKV = (h @ Wqkv^T + b) * mask     [4096 x 2304]
    gemm_bias<<<dim3(3*HID/64, M_TOK/64), 256, 0, stream>>>(
        h, Wqkv_w + (size_t)l*3*HID*HID, Wqkv_b + (size_t)l*3*HID, maskf,
        qkvb, 3*HID, HID);

    // attention
    attn_kernel<<<BQ*NH*SQ, SQ, 0, stream>>>(qkvb, kbt, maskf, attnb);

    // t = attn @ attn_out_w^T + b       [4096 x 768]
    gemm_bias<<<dim3(HID/64, M_TOK/64), 256, 0, stream>>>(
        attnb, attn_out_w + (size_t)l*HID*HID, attn_out_b + (size_t)l*HID, nullptr,
        tbuf, HID, HID);

    // ao = LN(t + h) * mask
    ln_res_kernel<<<M_TOK, 256, 0, stream>>>(tbuf, h, ln1_g + (size_t)l*HID,
                                             ln1_b + (size_t)l*HID, maskf, ao);

    // x = gelu(ao @ Wa^T) * (ao @ Wb^T) [4096 x 3072]
    gemm_glu<<<dim3(INTER/64, M_TOK/64), 256, 0, stream>>>(
        ao, glu_w + (size_t)l*2*INTER*HID,
        glu_w + (size_t)l*2*INTER*HID + (size_t)INTER*HID, xbuf, HID);

    // t = x @ wo^T + wo_b               [4096 x 768]
    gemm_bias<<<dim3(HID/64, M_TOK/64), 256, 0, stream>>>(
        xbuf, wo_w + (size_t)l*HID*INTER, wo_b + (size_t)l*HID, nullptr,
        tbuf, HID, INTER);

    // h = LN(t + ao) * mask
    ln_res_kernel<<<M_TOK, 256, 0, stream>>>(tbuf, ao, ln2_g + (size_t)l*HID,
                                             ln2_b + (size_t)l*HID, maskf, h);
  }

  copy_out_kernel<<<(M_TOK*HID + 255)/256, 256, 0, stream>>>(h, (float*)d_out);
}

// Round 3
// 1516.649 us; speedup vs baseline: 6.1568x; 6.1568x over previous
//
#include <hip/hip_runtime.h>
#include <hip/hip_bf16.h>
#include <math.h>

// Problem dims
#define BQ 8
#define SQ 512
#define HID 768
#define NH 12
#define DH 64
#define INTER 3072
#define NL 4
#define M_TOK (BQ*SQ)   // 4096 tokens

typedef unsigned short ushort_t;
typedef __attribute__((ext_vector_type(8))) short bf16x8;
typedef __attribute__((ext_vector_type(4))) float f32x4;

__device__ __forceinline__ float bf2f(ushort_t u) {
  union { float f; unsigned int i; } v; v.i = ((unsigned int)u) << 16; return v.f;
}
__device__ __forceinline__ ushort_t f2bf(float f) {
  __hip_bfloat16 h = __float2bfloat16(f);
  return *reinterpret_cast<ushort_t*>(&h);
}

__device__ __forceinline__ void gload_lds16(const ushort_t* g, ushort_t* l) {
  __builtin_amdgcn_global_load_lds(
      (const __attribute__((address_space(1))) void*)g,
      (__attribute__((address_space(3))) void*)l, 16, 0, 0);
}

// ---------------------------------------------------------------------------
// prep: maskf, maskbias, h = hidden*mask (fp32) + hb (bf16)
// ---------------------------------------------------------------------------
__global__ __launch_bounds__(256) void prep_kernel(
    const float* __restrict__ hidden, const float* __restrict__ amask,
    float* __restrict__ maskf, float* __restrict__ maskbias,
    float* __restrict__ h, ushort_t* __restrict__ hb)
{
  int i = blockIdx.x * 256 + threadIdx.x;
  if (i < M_TOK * HID) {
    float m = amask[i / HID];
    float v = hidden[i] * m;
    h[i] = v;
    hb[i] = f2bf(v);
    if (i < M_TOK) {
      maskf[i] = amask[i];
      maskbias[i] = (1.0f - amask[i]) * (-10000.0f);
    }
  }
}

// ---------------------------------------------------------------------------
// KERPLE bias table
// ---------------------------------------------------------------------------
__global__ void kerple_kernel(const float* __restrict__ r1,
                              const float* __restrict__ r2,
                              const float* __restrict__ r3,
                              float* __restrict__ kbt)
{
  int hh = blockIdx.x;
  int d  = threadIdx.x;
  float c1 = fmaxf(r1[hh], 1e-7f);
  float c2 = fmaxf(r2[hh], 1e-7f);
  float c3 = fmaxf(r3[hh], 1e-7f);
  float v = 0.0f;
  if (d > 0) v = -c1 * log1pf(c2 * powf((float)d, c3));
  kbt[hh * SQ + d] = v;
}

// ---------------------------------------------------------------------------
// weight cast fp32 -> bf16
// ---------------------------------------------------------------------------
__global__ __launch_bounds__(256) void wcast_kernel(
    const float* __restrict__ src, ushort_t* __restrict__ dst, int n)
{
  int i = (blockIdx.x * 256 + threadIdx.x) * 4;
  if (i < n) {
    float4 v = *reinterpret_cast<const float4*>(src + i);
    ushort4 o;
    o.x = f2bf(v.x); o.y = f2bf(v.y); o.z = f2bf(v.z); o.w = f2bf(v.w);
    *reinterpret_cast<ushort4*>(dst + i) = o;
  }
}

// ---------------------------------------------------------------------------
// bf16 MFMA GEMM: C[M,N] = A[M,K] @ W[N,K]^T (+ epilogue)
// 128x128 tile, BK=64, 256 threads (4 waves, 2x2 of 64x64), fp32 accum.
// NB=2: second B operand (GLU). EPI=0: +bias -> fp32 C. EPI=1: GLU -> bf16.
// LDS tiles are XOR-swizzled (source-side) so ds_read_b128 is conflict-free.
// ---------------------------------------------------------------------------
template<int NB, int EPI>
__global__ __launch_bounds__(256, 2) void mfma_gemm(
    const ushort_t* __restrict__ A, const ushort_t* __restrict__ B0p,
    const ushort_t* __restrict__ B1p, const float* __restrict__ bias,
    float* __restrict__ Cf, ushort_t* __restrict__ Cb, int N, int K)
{
  __shared__ ushort_t As_[128 * 64];
  __shared__ ushort_t Bs_[NB][128 * 64];
  int tid = threadIdx.x;
  int lane = tid & 63, w = tid >> 6;
  int wr = w >> 1, wc = w & 1;
  int bn = blockIdx.x, bm = blockIdx.y;

  f32x4 acc[NB][4][4];
#pragma unroll
  for (int p = 0; p < NB; ++p)
#pragma unroll
    for (int m = 0; m < 4; ++m)
#pragma unroll
      for (int n = 0; n < 4; ++n) acc[p][m][n] = (f32x4){0.f, 0.f, 0.f, 0.f};

  // staging geometry: tile = 128 rows x 128 B; wave stages 4 KB = 4 issues.
  int sr[4], sc[4], so[4];
#pragma unroll
  for (int i = 0; i < 4; ++i) {
    int o = w * 4096 + i * 1024 + lane * 16;   // byte offset in tile
    sr[i] = o >> 7;                            // row
    int cl = (o >> 4) & 7;                     // linear 16B chunk in row
    sc[i] = cl ^ (sr[i] & 7);                  // swizzled source chunk
    so[i] = (w * 4096 + i * 1024) >> 1;        // wave-uniform LDS elem base
  }
  const ushort_t* Arow  = A   + (size_t)bm * 128 * K;
  const ushort_t* Brow0 = B0p + (size_t)bn * 128 * K;
  const ushort_t* Brow1 = (NB == 2) ? (B1p + (size_t)bn * 128 * K) : nullptr;

  // fragment LDS element offsets (swizzled read): row r, chunk (kh*4+(lane>>4))^(r&7)
  int aoff[4][2], boff[4][2];
#pragma unroll
  for (int m = 0; m < 4; ++m)
#pragma unroll
    for (int kh = 0; kh < 2; ++kh) {
      int ra = wr * 64 + m * 16 + (lane & 15);
      int rb = wc * 64 + m * 16 + (lane & 15);
      int ch = (kh * 4 + (lane >> 4)) ^ (lane & 7);  // (r&7)==(lane&7) here
      aoff[m][kh] = ra * 64 + ch * 8;
      boff[m][kh] = rb * 64 + ch * 8;
    }

  for (int k0 = 0; k0 < K; k0 += 64) {
#pragma unroll
    for (int i = 0; i < 4; ++i)
      gload_lds16(Arow + (size_t)sr[i] * K + k0 + sc[i] * 8, As_ + so[i]);
#pragma unroll
    for (int i = 0; i < 4; ++i)
      gload_lds16(Brow0 + (size_t)sr[i] * K + k0 + sc[i] * 8, &Bs_[0][so[i]]);
    if constexpr (NB == 2) {
#pragma unroll
      for (int i = 0; i < 4; ++i)
        gload_lds16(Brow1 + (size_t)sr[i] * K + k0 + sc[i] * 8, &Bs_[1][so[i]]);
    }
    __syncthreads();
#pragma unroll
    for (int kh = 0; kh < 2; ++kh) {
      bf16x8 af[4], bf_[4];
#pragma unroll
      for (int m = 0; m < 4; ++m) af[m] = *(const bf16x8*)(As_ + aoff[m][kh]);
#pragma unroll
      for (int n = 0; n < 4; ++n) bf_[n] = *(const bf16x8*)(&Bs_[0][boff[n][kh]]);
#pragma unroll
      for (int m = 0; m < 4; ++m)
#pragma unroll
        for (int n = 0; n < 4; ++n)
          acc[0][m][n] = __builtin_amdgcn_mfma_f32_16x16x32_bf16(
              af[m], bf_[n], acc[0][m][n], 0, 0, 0);
      if constexpr (NB == 2) {
        bf16x8 bg[4];
#pragma unroll
        for (int n = 0; n < 4; ++n) bg[n] = *(const bf16x8*)(&Bs_[1][boff[n][kh]]);
#pragma unroll
        for (int m = 0; m < 4; ++m)
#pragma unroll
          for (int n = 0; n < 4; ++n)
            acc[1][m][n] = __builtin_amdgcn_mfma_f32_16x16x32_bf16(
                af[m], bg[n], acc[1][m][n], 0, 0, 0);
      }
    }
    __syncthreads();
  }

  // epilogue: C/D layout col=lane&15, row=(lane>>4)*4+j  [m89-verified]
  int r0 = bm * 128 + wr * 64, c0 = bn * 128 + wc * 64;
#pragma unroll
  for (int m = 0; m < 4; ++m)
#pragma unroll
    for (int n = 0; n < 4; ++n) {
      int col  = c0 + n * 16 + (lane & 15);
      int rowb = r0 + m * 16 + (lane >> 4) * 4;
      if constexpr (EPI == 0) {
        float bv = bias ? bias[col] : 0.0f;
#pragma unroll
        for (int j = 0; j < 4; ++j)
          Cf[(size_t)(rowb + j) * N + col] = acc[0][m][n][j] + bv;
      } else {
#pragma unroll
        for (int j = 0; j < 4; ++j) {
          float va = acc[0][m][n][j];
          float vb = acc[1][m][n][j];
          float ge = 0.5f * va * (1.0f + erff(va * 0.70710678118654752440f));
          Cb[(size_t)(rowb + j) * N + col] = f2bf(ge * vb);
        }
      }
    }
}

// ---------------------------------------------------------------------------
// Tiled attention: one block per (b, head, 64-row q-tile). 256 threads.
// Online softmax over 8 key-chunks of 64. Output bf16 (feeds attn_out GEMM).
// ---------------------------------------------------------------------------
__global__ __launch_bounds__(256) void attn_tile(
    const float* __restrict__ qkv, const float* __restrict__ kbt,
    const float* __restrict__ maskbias, ushort_t* __restrict__ attnb)
{
  __shared__ float    Qs[64][68];
  __shared__ float    Vs[64][68];
  __shared__ ushort_t Kb[64][68];
  __shared__ float    Sc[64][65];
  int tid = threadIdx.x;
  int bid = blockIdx.x;
  int qt = bid & 7;
  int hh = (bid >> 3) % NH;
  int b  = bid / (8 * NH);
  int q0 = qt * 64;
  int sr = tid >> 2, sg = tid & 3;       // staging/stats: 4 threads per row
  int tx = tid & 15, ty = tid >> 4;      // score compute: 16x16, 4x4 each

  { // stage Q tile (fp32)
    const float* src = qkv + (size_t)(b * SQ + q0 + sr) * (3 * HID) + hh * DH + sg * 16;
#pragma unroll
    for (int i = 0; i < 4; ++i)
      *reinterpret_cast<float4*>(&Qs[sr][sg * 16 + i * 4]) =
          *reinterpret_cast<const float4*>(src + i * 4);
  }
  float m_run = -1e30f, ssum = 0.0f;
  f32x4 o4[4];
#pragma unroll
  for (int u = 0; u < 4; ++u) o4[u] = (f32x4){0.f, 0.f, 0.f, 0.f};

  for (int c = 0; c < 8; ++c) {
    __syncthreads();   // Q staged / previous PV readers done
    { // stage K (bf16) + V (fp32) chunk
      const float* ks = qkv + (size_t)(b * SQ + c * 64 + sr) * (3 * HID) + HID + hh * DH + sg * 16;
      const float* vs = ks + HID;
#pragma unroll
      for (int i = 0; i < 4; ++i) {
        float4 kv = *reinterpret_cast<const float4*>(ks + i * 4);
        float4 vv = *reinterpret_cast<const float4*>(vs + i * 4);
        ushort4 pk;
        pk.x = f2bf(kv.x); pk.y = f2bf(kv.y); pk.z = f2bf(kv.z); pk.w = f2bf(kv.w);
        *reinterpret_cast<ushort4*>(&Kb[sr][sg * 16 + i * 4]) = pk;
        *reinterpret_cast<float4*>(&Vs[sr][sg * 16 + i * 4]) = vv;
      }
    }
    __syncthreads();
    // scores: 4q x 4k per thread
    float accs[4][4] = {};
#pragma unroll 4
    for (int d4 = 0; d4 < 16; ++d4) {
      float4 qv[4];
#pragma unroll
      for (int i = 0; i < 4; ++i)
        qv[i] = *reinterpret_cast<const float4*>(&Qs[ty * 4 + i][d4 * 4]);
      float4 kf[4];
#pragma unroll
      for (int j = 0; j < 4; ++j) {
        ushort4 ku = *reinterpret_cast<const ushort4*>(&Kb[tx * 4 + j][d4 * 4]);
        kf[j] = (float4){bf2f(ku.x), bf2f(ku.y), bf2f(ku.z), bf2f(ku.w)};
      }
#pragma unroll
      for (int i = 0; i < 4; ++i)
#pragma unroll
        for (int j = 0; j < 4; ++j)
          accs[i][j] += qv[i].x * kf[j].x + qv[i].y * kf[j].y
                      + qv[i].z * kf[j].z + qv[i].w * kf[j].w;
    }
#pragma unroll
    for (int i = 0; i < 4; ++i) {
      int qg = q0 + ty * 4 + i;
#pragma unroll
      for (int j = 0; j < 4; ++j) {
        int kg = c * 64 + tx * 4 + j;
        Sc[ty * 4 + i][tx * 4 + j] = accs[i][j] * 0.125f
            + maskbias[b * SQ + kg] + kbt[hh * SQ + abs(qg - kg)];
      }
    }
    __syncthreads();
    // stats: row sr, 4-lane segments, shfl reduce
    float sv[16];
    float lm = -1e30f;
#pragma unroll
    for (int k = 0; k < 16; ++k) { sv[k] = Sc[sr][sg * 16 + k]; lm = fmaxf(lm, sv[k]); }
    lm = fmaxf(lm, __shfl_xor(lm, 1));
    lm = fmaxf(lm, __shfl_xor(lm, 2));
    float mnew  = fmaxf(m_run, lm);
    float scale = __expf(m_run - mnew);
    float ps = 0.0f;
#pragma unroll
    for (int k = 0; k < 16; ++k) {
      float p = __expf(sv[k] - mnew);
      Sc[sr][sg * 16 + k] = p;
      ps += p;
    }
    ps += __shfl_xor(ps, 1);
    ps += __shfl_xor(ps, 2);
    ssum = ssum * scale + ps;
    m_run = mnew;
#pragma unroll
    for (int u = 0; u < 4; ++u) o4[u] *= scale;
    __syncthreads();
    // PV: o[d] += p[k] * V[k][d]
    for (int k = 0; k < 64; ++k) {
      float p = Sc[sr][k];
#pragma unroll
      for (int u = 0; u < 4; ++u) {
        float4 v = *reinterpret_cast<const float4*>(&Vs[k][sg * 16 + u * 4]);
        o4[u].x += p * v.x; o4[u].y += p * v.y;
        o4[u].z += p * v.z; o4[u].w += p * v.w;
      }
    }
  }
  float inv = 1.0f / ssum;
  size_t obase = (size_t)(b * SQ + q0 + sr) * HID + hh * DH + sg * 16;
#pragma unroll
  for (int u = 0; u < 4; ++u) {
    ushort4 pw;
    pw.x = f2bf(o4[u].x * inv); pw.y = f2bf(o4[u].y * inv);
    pw.z = f2bf(o4[u].z * inv); pw.w = f2bf(o4[u].w * inv);
    *reinterpret_cast<ushort4*>(attnb + obase + u * 4) = pw;
  }
}

// ---------------------------------------------------------------------------
// Residual + LayerNorm + mask: fp32 out + bf16 out
// ---------------------------------------------------------------------------
__global__ __launch_bounds__(256) void ln_res_kernel(
    const float* __restrict__ t, const float* __restrict__ res,
    const float* __restrict__ g, const float* __restrict__ bb,
    const float* __restrict__ maskf, float* __restrict__ out,
    ushort_t* __restrict__ outb)
{
  __shared__ float red[256];
  int row = blockIdx.x, tid = threadIdx.x;
  const float* tp = t   + (size_t)row * HID;
  const float* rp = res + (size_t)row * HID;
  float y0 = tp[tid      ] + rp[tid      ];
  float y1 = tp[tid + 256] + rp[tid + 256];
  float y2 = tp[tid + 512] + rp[tid + 512];

  red[tid] = y0 + y1 + y2; __syncthreads();
  for (int off = 128; off > 0; off >>= 1) {
    if (tid < off) red[tid] += red[tid + off];
    __syncthreads();
  }
  float mu = red[0] * (1.0f / 768.0f); __syncthreads();
  float d0 = y0 - mu, d1 = y1 - mu, d2 = y2 - mu;
  red[tid] = d0*d0 + d1*d1 + d2*d2; __syncthreads();
  for (int off = 128; off > 0; off >>= 1) {
    if (tid < off) red[tid] += red[tid + off];
    __syncthreads();
  }
  float rstd = rsqrtf(red[0] * (1.0f / 768.0f) + 1e-12f);
  float mk = maskf[row];
  float v0 = (d0*rstd*g[tid      ] + bb[tid      ]) * mk;
  float v1 = (d1*rstd*g[tid + 256] + bb[tid + 256]) * mk;
  float v2 = (d2*rstd*g[tid + 512] + bb[tid + 512]) * mk;
  size_t base = (size_t)row * HID;
  out[base + tid      ] = v0;  outb[base + tid      ] = f2bf(v0);
  out[base + tid + 256] = v1;  outb[base + tid + 256] = f2bf(v1);
  out[base + tid + 512] = v2;  outb[base + tid + 512] = f2bf(v2);
}

// ---------------------------------------------------------------------------
__global__ __launch_bounds__(256) void copy_out_kernel(
    const float* __restrict__ h, float* __restrict__ out)
{
  int i = blockIdx.x * 256 + threadIdx.x;
  if (i < M_TOK * HID) out[i] = h[i];
}

// ---------------------------------------------------------------------------
extern "C" void kernel_launch(void* const* d_in, const int* in_sizes, int n_in,
                              void* d_out, int out_size, void* d_ws, size_t ws_size,
                              hipStream_t stream) {
  const float* hidden     = (const float*)d_in[0];
  const float* amask      = (const float*)d_in[1];
  const float* Wqkv_w     = (const float*)d_in[2];
  const float* Wqkv_b     = (const float*)d_in[3];
  const float* attn_out_w = (const float*)d_in[4];
  const float* attn_out_b = (const float*)d_in[5];
  const float* ln1_g      = (const float*)d_in[6];
  const float* ln1_b      = (const float*)d_in[7];
  const float* glu_w      = (const float*)d_in[8];
  const float* wo_w       = (const float*)d_in[9];
  const float* wo_b       = (const float*)d_in[10];
  const float* ln2_g      = (const float*)d_in[11];
  const float* ln2_b      = (const float*)d_in[12];
  const float* r1         = (const float*)d_in[13];
  const float* r2         = (const float*)d_in[14];
  const float* r3         = (const float*)d_in[15];

  // workspace layout
  float* ws       = (float*)d_ws;
  float* maskf    = ws;                          // 4096
  float* maskbias = maskf    + 4096;             // 4096
  float* kbt      = maskbias + 4096;             // 6144
  float* h        = kbt      + 6144;             // 3145728
  float* qkvb     = h     + (size_t)M_TOK*HID;   // 9437184
  float* tbuf     = qkvb  + (size_t)M_TOK*3*HID; // 3145728
  float* ao       = tbuf  + (size_t)M_TOK*HID;   // 3145728
  ushort_t* us    = (ushort_t*)(ao + (size_t)M_TOK*HID);
  ushort_t* hb    = us;                          // 3145728
  ushort_t* aob   = hb   + (size_t)M_TOK*HID;    // 3145728
  ushort_t* atnb  = aob  + (size_t)M_TOK*HID;    // 3145728
  ushort_t* xb    = atnb + (size_t)M_TOK*HID;    // 12582912
  ushort_t* wbf   = xb   + (size_t)M_TOK*INTER;  // 4718592

  prep_kernel<<<(M_TOK*HID + 255)/256, 256, 0, stream>>>(
      hidden, amask, maskf, maskbias, h, hb);

  for (int l = 0; l < NL; ++l) {
    kerple_kernel<<<NH, SQ, 0, stream>>>(r1 + l*NH, r2 + l*NH, r3 + l*NH, kbt);

    // ---- QKV = h @ Wqkv^T + b  [4096 x 2304] fp32 ----
    {
      int n = 3*HID*HID;
      wcast_kernel<<<(n/4 + 255)/256, 256, 0, stream>>>(
          Wqkv_w + (size_t)l*n, wbf, n);
      mfma_gemm<1,0><<<dim3(3*HID/128, M_TOK/128), 256, 0, stream>>>(
          hb, wbf, nullptr, Wqkv_b + (size_t)l*3*HID, qkvb, nullptr, 3*HID, HID);
    }

    // ---- attention -> atnb (bf16) ----
    attn_tile<<<BQ*NH*8, 256, 0, stream>>>(qkvb, kbt, maskbias, atnb);

    // ---- t = attn @ attn_out_w^T + b  [4096 x 768] fp32 ----
    {
      int n = HID*HID;
      wcast_kernel<<<(n/4 + 255)/256, 256, 0, stream>>>(
          attn_out_w + (size_t)l*n, wbf, n);
      mfma_gemm<1,0><<<dim3(HID/128, M_TOK/128), 256, 0, stream>>>(
          atnb, wbf, nullptr, attn_out_b + (size_t)l*HID, tbuf, nullptr, HID, HID);
    }

    // ---- ao = LN(t + h) * mask  (fp32 + bf16) ----
    ln_res_kernel<<<M_TOK, 256, 0, stream>>>(tbuf, h, ln1_g + (size_t)l*HID,
                                             ln1_b + (size_t)l*HID, maskf, ao, aob);

    // ---- x = gelu(ao @ Wa^T) * (ao @ Wb^T)  -> xb (bf16) [4096 x 3072] ----
    {
      int n = 2*INTER*HID;
      wcast_kernel<<<(n/4 + 255)/256, 256, 0, stream>>>(
          glu_w + (size_t)l*n, wbf, n);
      mfma_gemm<2,1><<<dim3(INTER/128, M_TOK/128), 256, 0, stream>>>(
          aob, wbf, wbf + (size_t)INTER*HID, nullptr, nullptr, xb, INTER, HID);
    }

    // ---- t = x @ wo^T + wo_b  [4096 x 768] fp32 ----
    {
      int n = HID*INTER;
      wcast_kernel<<<(n/4 + 255)/256, 256, 0, stream>>>(
          wo_w + (size_t)l*n, wbf, n);
      mfma_gemm<1,0><<<dim3(HID/128, M_TOK/128), 256, 0, stream>>>(
          xb, wbf, nullptr, wo_b + (size_t)l*HID, tbuf, nullptr, HID, INTER);
    }

    // ---- h = LN(t + ao) * mask  (fp32 + bf16) ----
    ln_res_kernel<<<M_TOK, 256, 0, stream>>>(tbuf, ao, ln2_g + (size_t)l*HID,
                                             ln2_b + (size_t)l*HID, maskf, h, hb);
  }

  copy_out_kernel<<<(M_TOK*HID + 255)/256, 256, 0, stream>>>(h, (float*)d_out);
}

// Round 4
// 909.313 us; speedup vs baseline: 10.2690x; 1.6679x over previous
//
#include <hip/hip_runtime.h>
#include <hip/hip_bf16.h>
#include <math.h>

// Problem dims
#define BQ 8
#define SQ 512
#define HID 768
#define NH 12
#define DH 64
#define INTER 3072
#define NL 4
#define M_TOK (BQ*SQ)   // 4096 tokens

typedef unsigned short ushort_t;
typedef __attribute__((ext_vector_type(8))) short bf16x8;
typedef __attribute__((ext_vector_type(8))) unsigned short u16x8;
typedef __attribute__((ext_vector_type(4))) float f32x4;

__device__ __forceinline__ float bf2f(ushort_t u) {
  union { float f; unsigned int i; } v; v.i = ((unsigned int)u) << 16; return v.f;
}
__device__ __forceinline__ ushort_t f2bf(float f) {
  __hip_bfloat16 h = __float2bfloat16(f);
  return *reinterpret_cast<ushort_t*>(&h);
}

__device__ __forceinline__ void gload_lds16(const ushort_t* g, ushort_t* l) {
  __builtin_amdgcn_global_load_lds(
      (const __attribute__((address_space(1))) void*)g,
      (__attribute__((address_space(3))) void*)l, 16, 0, 0);
}

// ---------------------------------------------------------------------------
// prep: maskf, maskbias, h = hidden*mask (fp32) + hb (bf16)
// ---------------------------------------------------------------------------
__global__ __launch_bounds__(256) void prep_kernel(
    const float* __restrict__ hidden, const float* __restrict__ amask,
    float* __restrict__ maskf, float* __restrict__ maskbias,
    float* __restrict__ h, ushort_t* __restrict__ hb)
{
  int i = blockIdx.x * 256 + threadIdx.x;
  if (i < M_TOK * HID) {
    float m = amask[i / HID];
    float v = hidden[i] * m;
    h[i] = v;
    hb[i] = f2bf(v);
    if (i < M_TOK) {
      maskf[i] = amask[i];
      maskbias[i] = (1.0f - amask[i]) * (-10000.0f);
    }
  }
}

// ---------------------------------------------------------------------------
// KERPLE bias table
// ---------------------------------------------------------------------------
__global__ void kerple_kernel(const float* __restrict__ r1,
                              const float* __restrict__ r2,
                              const float* __restrict__ r3,
                              float* __restrict__ kbt)
{
  int hh = blockIdx.x;
  int d  = threadIdx.x;
  float c1 = fmaxf(r1[hh], 1e-7f);
  float c2 = fmaxf(r2[hh], 1e-7f);
  float c3 = fmaxf(r3[hh], 1e-7f);
  float v = 0.0f;
  if (d > 0) v = -c1 * log1pf(c2 * powf((float)d, c3));
  kbt[hh * SQ + d] = v;
}

// ---------------------------------------------------------------------------
// weight cast fp32 -> bf16
// ---------------------------------------------------------------------------
__global__ __launch_bounds__(256) void wcast_kernel(
    const float* __restrict__ src, ushort_t* __restrict__ dst, int n)
{
  int i = (blockIdx.x * 256 + threadIdx.x) * 4;
  if (i < n) {
    float4 v = *reinterpret_cast<const float4*>(src + i);
    ushort4 o;
    o.x = f2bf(v.x); o.y = f2bf(v.y); o.z = f2bf(v.z); o.w = f2bf(v.w);
    *reinterpret_cast<ushort4*>(dst + i) = o;
  }
}

// ---------------------------------------------------------------------------
// bf16 MFMA GEMM: C[M,N] = A[M,K] @ W[N,K]^T (+ epilogue)
// 128x128 tile, BK=64, 256 threads (4 waves, 2x2 of 64x64), fp32 accum.
// EPI=0: +bias -> fp32 Cf.  EPI=1: GLU(gelu(a)*b) -> bf16 Cb.
// EPI=2: (+bias)*rowscale -> bf16 Cb.
// ---------------------------------------------------------------------------
template<int NB, int EPI>
__global__ __launch_bounds__(256, 2) void mfma_gemm(
    const ushort_t* __restrict__ A, const ushort_t* __restrict__ B0p,
    const ushort_t* __restrict__ B1p, const float* __restrict__ bias,
    const float* __restrict__ rowscale,
    float* __restrict__ Cf, ushort_t* __restrict__ Cb, int N, int K)
{
  __shared__ ushort_t As_[128 * 64];
  __shared__ ushort_t Bs_[NB][128 * 64];
  int tid = threadIdx.x;
  int lane = tid & 63, w = tid >> 6;
  int wr = w >> 1, wc = w & 1;
  int bn = blockIdx.x, bm = blockIdx.y;

  f32x4 acc[NB][4][4];
#pragma unroll
  for (int p = 0; p < NB; ++p)
#pragma unroll
    for (int m = 0; m < 4; ++m)
#pragma unroll
      for (int n = 0; n < 4; ++n) acc[p][m][n] = (f32x4){0.f, 0.f, 0.f, 0.f};

  int sr[4], sc[4], so[4];
#pragma unroll
  for (int i = 0; i < 4; ++i) {
    int o = w * 4096 + i * 1024 + lane * 16;   // byte offset in tile
    sr[i] = o >> 7;                            // row
    int cl = (o >> 4) & 7;                     // linear 16B chunk in row
    sc[i] = cl ^ (sr[i] & 7);                  // swizzled source chunk
    so[i] = (w * 4096 + i * 1024) >> 1;        // wave-uniform LDS elem base
  }
  const ushort_t* Arow  = A   + (size_t)bm * 128 * K;
  const ushort_t* Brow0 = B0p + (size_t)bn * 128 * K;
  const ushort_t* Brow1 = (NB == 2) ? (B1p + (size_t)bn * 128 * K) : nullptr;

  int aoff[4][2], boff[4][2];
#pragma unroll
  for (int m = 0; m < 4; ++m)
#pragma unroll
    for (int kh = 0; kh < 2; ++kh) {
      int ra = wr * 64 + m * 16 + (lane & 15);
      int rb = wc * 64 + m * 16 + (lane & 15);
      int ch = (kh * 4 + (lane >> 4)) ^ (lane & 7);
      aoff[m][kh] = ra * 64 + ch * 8;
      boff[m][kh] = rb * 64 + ch * 8;
    }

  for (int k0 = 0; k0 < K; k0 += 64) {
#pragma unroll
    for (int i = 0; i < 4; ++i)
      gload_lds16(Arow + (size_t)sr[i] * K + k0 + sc[i] * 8, As_ + so[i]);
#pragma unroll
    for (int i = 0; i < 4; ++i)
      gload_lds16(Brow0 + (size_t)sr[i] * K + k0 + sc[i] * 8, &Bs_[0][so[i]]);
    if constexpr (NB == 2) {
#pragma unroll
      for (int i = 0; i < 4; ++i)
        gload_lds16(Brow1 + (size_t)sr[i] * K + k0 + sc[i] * 8, &Bs_[1][so[i]]);
    }
    __syncthreads();
#pragma unroll
    for (int kh = 0; kh < 2; ++kh) {
      bf16x8 af[4], bf_[4];
#pragma unroll
      for (int m = 0; m < 4; ++m) af[m] = *(const bf16x8*)(As_ + aoff[m][kh]);
#pragma unroll
      for (int n = 0; n < 4; ++n) bf_[n] = *(const bf16x8*)(&Bs_[0][boff[n][kh]]);
#pragma unroll
      for (int m = 0; m < 4; ++m)
#pragma unroll
        for (int n = 0; n < 4; ++n)
          acc[0][m][n] = __builtin_amdgcn_mfma_f32_16x16x32_bf16(
              af[m], bf_[n], acc[0][m][n], 0, 0, 0);
      if constexpr (NB == 2) {
        bf16x8 bg[4];
#pragma unroll
        for (int n = 0; n < 4; ++n) bg[n] = *(const bf16x8*)(&Bs_[1][boff[n][kh]]);
#pragma unroll
        for (int m = 0; m < 4; ++m)
#pragma unroll
          for (int n = 0; n < 4; ++n)
            acc[1][m][n] = __builtin_amdgcn_mfma_f32_16x16x32_bf16(
                af[m], bg[n], acc[1][m][n], 0, 0, 0);
      }
    }
    __syncthreads();
  }

  // epilogue: C/D layout col=lane&15, row=(lane>>4)*4+j
  int r0 = bm * 128 + wr * 64, c0 = bn * 128 + wc * 64;
#pragma unroll
  for (int m = 0; m < 4; ++m)
#pragma unroll
    for (int n = 0; n < 4; ++n) {
      int col  = c0 + n * 16 + (lane & 15);
      int rowb = r0 + m * 16 + (lane >> 4) * 4;
      if constexpr (EPI == 0) {
        float bv = bias ? bias[col] : 0.0f;
#pragma unroll
        for (int j = 0; j < 4; ++j)
          Cf[(size_t)(rowb + j) * N + col] = acc[0][m][n][j] + bv;
      } else if constexpr (EPI == 1) {
#pragma unroll
        for (int j = 0; j < 4; ++j) {
          float va = acc[0][m][n][j];
          float vb = acc[1][m][n][j];
          float ge = 0.5f * va * (1.0f + erff(va * 0.70710678118654752440f));
          Cb[(size_t)(rowb + j) * N + col] = f2bf(ge * vb);
        }
      } else {
        float bv = bias ? bias[col] : 0.0f;
#pragma unroll
        for (int j = 0; j < 4; ++j) {
          float v = (acc[0][m][n][j] + bv) * (rowscale ? rowscale[rowb + j] : 1.0f);
          Cb[(size_t)(rowb + j) * N + col] = f2bf(v);
        }
      }
    }
}

// ---------------------------------------------------------------------------
// MFMA flash attention. One block per (b, head, 64-q-tile); 4 waves x 16 q.
// qkvb is bf16 [token][3*HID]. Online softmax over 8 key-chunks of 64.
// LDS tiles XOR-swizzled at 16B-chunk granularity: elem (row, k) lives at
// row*64 + ((k>>3) ^ (row&7))*8 + (k&7).
// ---------------------------------------------------------------------------
__global__ __launch_bounds__(256) void attn_mfma(
    const ushort_t* __restrict__ qkvb, const float* __restrict__ kbt,
    const float* __restrict__ maskbias, ushort_t* __restrict__ attnb)
{
  __shared__ ushort_t Ks[64 * 64];   // K[k][d]
  __shared__ ushort_t Vt[64 * 64];   // V^T[d][k]
  __shared__ ushort_t Ps[64 * 64];   // P[q][k] (per-wave 16-row slices)
  __shared__ float    kbs[SQ];
  __shared__ float    mbs[SQ];

  int tid  = threadIdx.x;
  int lane = tid & 63, w = tid >> 6;
  int g = lane >> 4, r = lane & 15;
  int bid = blockIdx.x;
  int qt = bid & 7;
  int hh = (bid >> 3) % NH;
  int b  = bid / (8 * NH);
  int q0 = qt * 64;

  for (int i = tid; i < SQ; i += 256) {
    kbs[i] = kbt[hh * SQ + i];
    mbs[i] = maskbias[b * SQ + i];
  }

  // Q fragments hoisted to registers: row q0+w*16+r, d = g*8 + kh*32
  bf16x8 qf[2];
  {
    const ushort_t* qsrc = qkvb + (size_t)(b * SQ + q0 + w * 16 + r) * (3 * HID)
                         + hh * DH + g * 8;
    qf[0] = *(const bf16x8*)(qsrc);
    qf[1] = *(const bf16x8*)(qsrc + 32);
  }

  float m_run[4], l_run[4];
  f32x4 oacc[4];
#pragma unroll
  for (int j = 0; j < 4; ++j) { m_run[j] = -1e30f; l_run[j] = 0.f; }
#pragma unroll
  for (int nd = 0; nd < 4; ++nd) oacc[nd] = (f32x4){0.f, 0.f, 0.f, 0.f};

  int k2 = (tid & 31) * 2, dg = tid >> 5;   // Vt staging assignment

  for (int kc = 0; kc < 8; ++kc) {
    __syncthreads();
    // ---- stage K via global_load_lds (pre-swizzled source, linear dest) ----
#pragma unroll
    for (int ii = 0; ii < 2; ++ii) {
      int row = (w * 2 + ii) * 8 + (lane >> 3);
      int c   = lane & 7;
      const ushort_t* src = qkvb + (size_t)(b * SQ + kc * 64 + row) * (3 * HID)
                          + HID + hh * DH + ((c ^ (row & 7)) * 8);
      gload_lds16(src, Ks + (w * 2 + ii) * 512 + lane * 8);
    }
    // ---- stage V^T (packed ushort2 writes, conflict-free) ----
    {
      const ushort_t* v0 = qkvb + (size_t)(b * SQ + kc * 64 + k2) * (3 * HID)
                         + 2 * HID + hh * DH + dg * 8;
      const ushort_t* v1 = v0 + 3 * HID;
      u16x8 a = *(const u16x8*)v0;
      u16x8 c = *(const u16x8*)v1;
#pragma unroll
      for (int u = 0; u < 8; ++u) {
        int d = dg * 8 + u;
        int addr = d * 64 + (((k2 >> 3) ^ (d & 7)) * 8) + (k2 & 7);
        ushort2 pr; pr.x = (ushort_t)a[u]; pr.y = (ushort_t)c[u];
        *(ushort2*)(Vt + addr) = pr;
      }
    }
    __syncthreads();

    // ---- QK^T: S[16 q][64 k] per wave ----
    f32x4 sacc[4];
#pragma unroll
    for (int n = 0; n < 4; ++n) sacc[n] = (f32x4){0.f, 0.f, 0.f, 0.f};
#pragma unroll
    for (int kh = 0; kh < 2; ++kh) {
#pragma unroll
      for (int n = 0; n < 4; ++n) {
        bf16x8 kf = *(const bf16x8*)(Ks + (n * 16 + r) * 64
                                     + (((g + kh * 4) ^ (r & 7)) * 8));
        sacc[n] = __builtin_amdgcn_mfma_f32_16x16x32_bf16(qf[kh], kf, sacc[n], 0, 0, 0);
      }
    }

    // ---- bias + online softmax (D layout: col k=n*16+r, row q=g*4+j) ----
    float sval[4][4], mx[4];
#pragma unroll
    for (int j = 0; j < 4; ++j) mx[j] = -1e30f;
#pragma unroll
    for (int n = 0; n < 4; ++n) {
      int kg = kc * 64 + n * 16 + r;
      float mb = mbs[kg];
#pragma unroll
      for (int j = 0; j < 4; ++j) {
        int qg = q0 + w * 16 + g * 4 + j;
        float s = sacc[n][j] * 0.125f + mb + kbs[abs(qg - kg)];
        sval[n][j] = s;
        mx[j] = fmaxf(mx[j], s);
      }
    }
#pragma unroll
    for (int j = 0; j < 4; ++j) {
      mx[j] = fmaxf(mx[j], __shfl_xor(mx[j], 1));
      mx[j] = fmaxf(mx[j], __shfl_xor(mx[j], 2));
      mx[j] = fmaxf(mx[j], __shfl_xor(mx[j], 4));
      mx[j] = fmaxf(mx[j], __shfl_xor(mx[j], 8));
      float mn = fmaxf(m_run[j], mx[j]);
      mx[j] = __expf(m_run[j] - mn);   // reuse as scale
      m_run[j] = mn;
    }
    float rs[4] = {0.f, 0.f, 0.f, 0.f};
#pragma unroll
    for (int n = 0; n < 4; ++n) {
#pragma unroll
      for (int j = 0; j < 4; ++j) {
        float pp = __expf(sval[n][j] - m_run[j]);
        int prow = w * 16 + g * 4 + j;
        int pcol = n * 16 + r;
        Ps[prow * 64 + (((pcol >> 3) ^ (prow & 7)) * 8) + (pcol & 7)] = f2bf(pp);
        rs[j] += pp;
      }
    }
#pragma unroll
    for (int j = 0; j < 4; ++j) {
      rs[j] += __shfl_xor(rs[j], 1);
      rs[j] += __shfl_xor(rs[j], 2);
      rs[j] += __shfl_xor(rs[j], 4);
      rs[j] += __shfl_xor(rs[j], 8);
      l_run[j] = l_run[j] * mx[j] + rs[j];
    }
#pragma unroll
    for (int nd = 0; nd < 4; ++nd)
#pragma unroll
      for (int j = 0; j < 4; ++j) oacc[nd][j] *= mx[j];

    // ---- PV: O[16 q][64 d] += P @ V (wave-local Ps; compiler orders LDS) ----
#pragma unroll
    for (int kh = 0; kh < 2; ++kh) {
      bf16x8 pa = *(const bf16x8*)(Ps + (w * 16 + r) * 64
                                   + (((g + kh * 4) ^ (r & 7)) * 8));
#pragma unroll
      for (int nd = 0; nd < 4; ++nd) {
        bf16x8 vf = *(const bf16x8*)(Vt + (nd * 16 + r) * 64
                                     + (((g + kh * 4) ^ (r & 7)) * 8));
        oacc[nd] = __builtin_amdgcn_mfma_f32_16x16x32_bf16(pa, vf, oacc[nd], 0, 0, 0);
      }
    }
  }

  // ---- epilogue ----
#pragma unroll
  for (int j = 0; j < 4; ++j) {
    float inv = 1.0f / l_run[j];
    int token = b * SQ + q0 + w * 16 + g * 4 + j;
#pragma unroll
    for (int nd = 0; nd < 4; ++nd)
      attnb[(size_t)token * HID + hh * DH + nd * 16 + r] = f2bf(oacc[nd][j] * inv);
  }
}

// ---------------------------------------------------------------------------
// Residual + LayerNorm + mask: fp32 out + bf16 out
// ---------------------------------------------------------------------------
__global__ __launch_bounds__(256) void ln_res_kernel(
    const float* __restrict__ t, const float* __restrict__ res,
    const float* __restrict__ g, const float* __restrict__ bb,
    const float* __restrict__ maskf, float* __restrict__ out,
    ushort_t* __restrict__ outb)
{
  __shared__ float red[256];
  int row = blockIdx.x, tid = threadIdx.x;
  const float* tp = t   + (size_t)row * HID;
  const float* rp = res + (size_t)row * HID;
  float y0 = tp[tid      ] + rp[tid      ];
  float y1 = tp[tid + 256] + rp[tid + 256];
  float y2 = tp[tid + 512] + rp[tid + 512];

  red[tid] = y0 + y1 + y2; __syncthreads();
  for (int off = 128; off > 0; off >>= 1) {
    if (tid < off) red[tid] += red[tid + off];
    __syncthreads();
  }
  float mu = red[0] * (1.0f / 768.0f); __syncthreads();
  float d0 = y0 - mu, d1 = y1 - mu, d2 = y2 - mu;
  red[tid] = d0*d0 + d1*d1 + d2*d2; __syncthreads();
  for (int off = 128; off > 0; off >>= 1) {
    if (tid < off) red[tid] += red[tid + off];
    __syncthreads();
  }
  float rstd = rsqrtf(red[0] * (1.0f / 768.0f) + 1e-12f);
  float mk = maskf[row];
  float v0 = (d0*rstd*g[tid      ] + bb[tid      ]) * mk;
  float v1 = (d1*rstd*g[tid + 256] + bb[tid + 256]) * mk;
  float v2 = (d2*rstd*g[tid + 512] + bb[tid + 512]) * mk;
  size_t base = (size_t)row * HID;
  out[base + tid      ] = v0;  outb[base + tid      ] = f2bf(v0);
  out[base + tid + 256] = v1;  outb[base + tid + 256] = f2bf(v1);
  out[base + tid + 512] = v2;  outb[base + tid + 512] = f2bf(v2);
}

// ---------------------------------------------------------------------------
__global__ __launch_bounds__(256) void copy_out_kernel(
    const float* __restrict__ h, float* __restrict__ out)
{
  int i = blockIdx.x * 256 + threadIdx.x;
  if (i < M_TOK * HID) out[i] = h[i];
}

// ---------------------------------------------------------------------------
extern "C" void kernel_launch(void* const* d_in, const int* in_sizes, int n_in,
                              void* d_out, int out_size, void* d_ws, size_t ws_size,
                              hipStream_t stream) {
  const float* hidden     = (const float*)d_in[0];
  const float* amask      = (const float*)d_in[1];
  const float* Wqkv_w     = (const float*)d_in[2];
  const float* Wqkv_b     = (const float*)d_in[3];
  const float* attn_out_w = (const float*)d_in[4];
  const float* attn_out_b = (const float*)d_in[5];
  const float* ln1_g      = (const float*)d_in[6];
  const float* ln1_b      = (const float*)d_in[7];
  const float* glu_w      = (const float*)d_in[8];
  const float* wo_w       = (const float*)d_in[9];
  const float* wo_b       = (const float*)d_in[10];
  const float* ln2_g      = (const float*)d_in[11];
  const float* ln2_b      = (const float*)d_in[12];
  const float* r1         = (const float*)d_in[13];
  const float* r2         = (const float*)d_in[14];
  const float* r3         = (const float*)d_in[15];

  // workspace layout
  float* ws       = (float*)d_ws;
  float* maskf    = ws;                          // 4096
  float* maskbias = maskf    + 4096;             // 4096
  float* kbt      = maskbias + 4096;             // 6144
  float* h        = kbt      + 6144;             // 3145728
  float* tbuf     = h    + (size_t)M_TOK*HID;    // 3145728
  float* ao       = tbuf + (size_t)M_TOK*HID;    // 3145728
  ushort_t* us    = (ushort_t*)(ao + (size_t)M_TOK*HID);
  ushort_t* hb    = us;                          // 3145728
  ushort_t* aob   = hb    + (size_t)M_TOK*HID;   // 3145728
  ushort_t* atnb  = aob   + (size_t)M_TOK*HID;   // 3145728
  ushort_t* xb    = atnb  + (size_t)M_TOK*HID;   // 12582912
  ushort_t* qkv_b = xb    + (size_t)M_TOK*INTER; // 9437184
  ushort_t* wbf   = qkv_b + (size_t)M_TOK*3*HID; // 4718592

  prep_kernel<<<(M_TOK*HID + 255)/256, 256, 0, stream>>>(
      hidden, amask, maskf, maskbias, h, hb);

  for (int l = 0; l < NL; ++l) {
    kerple_kernel<<<NH, SQ, 0, stream>>>(r1 + l*NH, r2 + l*NH, r3 + l*NH, kbt);

    // ---- qkv_b = (h @ Wqkv^T + b) * mask  [4096 x 2304] bf16 ----
    {
      int n = 3*HID*HID;
      wcast_kernel<<<(n/4 + 255)/256, 256, 0, stream>>>(
          Wqkv_w + (size_t)l*n, wbf, n);
      mfma_gemm<1,2><<<dim3(3*HID/128, M_TOK/128), 256, 0, stream>>>(
          hb, wbf, nullptr, Wqkv_b + (size_t)l*3*HID, maskf,
          nullptr, qkv_b, 3*HID, HID);
    }

    // ---- attention -> atnb (bf16) ----
    attn_mfma<<<BQ*NH*8, 256, 0, stream>>>(qkv_b, kbt, maskbias, atnb);

    // ---- t = attn @ attn_out_w^T + b  [4096 x 768] fp32 ----
    {
      int n = HID*HID;
      wcast_kernel<<<(n/4 + 255)/256, 256, 0, stream>>>(
          attn_out_w + (size_t)l*n, wbf, n);
      mfma_gemm<1,0><<<dim3(HID/128, M_TOK/128), 256, 0, stream>>>(
          atnb, wbf, nullptr, attn_out_b + (size_t)l*HID, nullptr,
          tbuf, nullptr, HID, HID);
    }

    // ---- ao = LN(t + h) * mask ----
    ln_res_kernel<<<M_TOK, 256, 0, stream>>>(tbuf, h, ln1_g + (size_t)l*HID,
                                             ln1_b + (size_t)l*HID, maskf, ao, aob);

    // ---- x = gelu(ao @ Wa^T) * (ao @ Wb^T)  -> xb (bf16) ----
    {
      int n = 2*INTER*HID;
      wcast_kernel<<<(n/4 + 255)/256, 256, 0, stream>>>(
          glu_w + (size_t)l*n, wbf, n);
      mfma_gemm<2,1><<<dim3(INTER/128, M_TOK/128), 256, 0, stream>>>(
          aob, wbf, wbf + (size_t)INTER*HID, nullptr, nullptr,
          nullptr, xb, INTER, HID);
    }

    // ---- t = x @ wo^T + wo_b  [4096 x 768] fp32 ----
    {
      int n = HID*INTER;
      wcast_kernel<<<(n/4 + 255)/256, 256, 0, stream>>>(
          wo_w + (size_t)l*n, wbf, n);
      mfma_gemm<1,0><<<dim3(HID/128, M_TOK/128), 256, 0, stream>>>(
          xb, wbf, nullptr, wo_b + (size_t)l*HID, nullptr,
          tbuf, nullptr, HID, INTER);
    }

    // ---- h = LN(t + ao) * mask ----
    ln_res_kernel<<<M_TOK, 256, 0, stream>>>(tbuf, ao, ln2_g + (size_t)l*HID,
                                             ln2_b + (size_t)l*HID, maskf, h, hb);
  }

  copy_out_kernel<<<(M_TOK*HID + 255)/256, 256, 0, stream>>>(h, (float*)d_out);
}